// Round 12
// baseline (532.652 us; speedup 1.0000x reference)
//
#include <hip/hip_runtime.h>
#include <hip/hip_bf16.h>
#include <math.h>

// ---------------------------------------------------------------------------
// MPNN node classifier.
// R11: (1) GEMM/FC v4 -- no LDS, no barriers: B fragments read directly from
// global (B[n][k] row-major == MFMA B-operand layout; B is L2-resident).
// (2) order-free bucket bases: per-bucket atomicAdd + in-block chunk scan
// (replaces the single-CU 65K serial scan); gather reads beg/end from
// rowptr/rowEnd so bucket order in `packed` no longer matters.
// ---------------------------------------------------------------------------

#define F_DIM 256   // F_IN == H == 256
#define C_DIM 40
#define NBUCK 256   // coarse buckets: dst >> 8
#define NB    256   // scatter blocks (chunks)
#define MAXCHUNK 6400

typedef _Float16 half8 __attribute__((ext_vector_type(8)));
typedef float    f32x4 __attribute__((ext_vector_type(4)));

// --- merged prep: blocks [0,NB) = bucket_count chunk histograms;
//     [NB,NB+256) w1 cvt; [NB+512) w2 cvt; [NB+768) wfc cvt+pad.
//     Block NB thread 0 also zeroes the bucket-base allocator counter.
__global__ __launch_bounds__(256) void prep(
    const int* __restrict__ dst, int* __restrict__ cntMat, int E, int chunk,
    const float* __restrict__ w1, const float* __restrict__ w2,
    const float* __restrict__ wfc, _Float16* __restrict__ w1t,
    _Float16* __restrict__ w2t, _Float16* __restrict__ wfcT,
    int* __restrict__ gctr)
{
    __shared__ int lcnt[NBUCK];
    const int tid = threadIdx.x;
    const int bid = blockIdx.x;
    if (bid < NB) {
        lcnt[tid] = 0;
        __syncthreads();
        const int e0 = bid * chunk;
        const int e1 = min(e0 + chunk, E);
        for (int i = e0 + tid; i < e1; i += 256)
            atomicAdd(&lcnt[dst[i] >> 8], 1);
        __syncthreads();
        cntMat[tid * NB + bid] = lcnt[tid];
    } else {
        if (bid == NB && tid == 0) *gctr = 0;
        const int r = bid - NB;
        const int k = r & 255;
        const int y = r >> 8;
        const int n = tid;
        if (y == 0)      w1t[n * 256 + k] = (_Float16)w1[k * 256 + n];
        else if (y == 1) w2t[n * 256 + k] = (_Float16)w2[k * 256 + n];
        else if (n < 48)
            wfcT[n * 256 + k] = (n < C_DIM) ? (_Float16)wfc[k * C_DIM + n]
                                            : (_Float16)0.f;
    }
}

// --- order-free bucket base allocation: block b scans its 256 chunk counts,
//     grabs a contiguous region via device-scope atomicAdd, writes per-chunk
//     bases and the bucket end.
__global__ __launch_bounds__(256) void bucket_alloc(
    const int* __restrict__ cntMat, int* __restrict__ baseMat,
    int* __restrict__ bEnd, int* __restrict__ gctr)
{
    __shared__ int segSum[4];
    __shared__ int baseSh;
    const int tid  = threadIdx.x;
    const int wave = tid >> 6;
    const int lane = tid & 63;
    const int b    = blockIdx.x;

    const int v = cntMat[b * NB + tid];
    int s = v;                              // inclusive wave scan
    #pragma unroll
    for (int off = 1; off < 64; off <<= 1) {
        const int t = __shfl_up(s, off, 64);
        if (lane >= off) s += t;
    }
    if (lane == 63) segSum[wave] = s;
    __syncthreads();
    if (tid == 0) {
        int c = 0;
        #pragma unroll
        for (int w = 0; w < 4; ++w) { const int t = segSum[w]; segSum[w] = c; c += t; }
        baseSh = atomicAdd(gctr, c);        // c = bucket total
    }
    __syncthreads();
    const int excl = baseSh + segSum[wave] + (s - v);
    baseMat[b * NB + tid] = excl;
    if (tid == 255) bEnd[b] = excl + v;
}

// --- MFMA fp16 GEMM v4: out[M x 256] = f16(relu(A[M x 256] @ Wt^T + bias))
//     Barrier-free, LDS-free: wave caches full A stripe in registers, reads
//     B fragments directly from global (Wt[n][k] row-major == B-operand
//     layout; Wt is L2-resident). Block = 128 rows, 4 waves.
template <bool AF32>
__global__ __launch_bounds__(256, 2) void gemm_f16(
    const void* __restrict__ Av, const _Float16* __restrict__ Wt,
    const float* __restrict__ bias, _Float16* __restrict__ out, int M)
{
    constexpr int K = 256;
    const int tid  = threadIdx.x;
    const int wave = tid >> 6;
    const int lane = tid & 63;
    const int quad = lane >> 4;
    const int l16  = lane & 15;
    const int row0 = blockIdx.x * 128;

    const int gr0 = min(row0 + wave * 32 + l16,      M - 1);
    const int gr1 = min(row0 + wave * 32 + 16 + l16, M - 1);

    // cache full A stripe: aReg[mi][kk] covers k = kk*32 + quad*8 .. +7
    half8 aReg[2][8];
    if constexpr (AF32) {
        const float* A = (const float*)Av;
        #pragma unroll
        for (int mi = 0; mi < 2; ++mi) {
            const int gr = mi ? gr1 : gr0;
            #pragma unroll
            for (int kk = 0; kk < 8; ++kk) {
                const float4 u0 = *(const float4*)(A + (size_t)gr * K + kk * 32 + quad * 8);
                const float4 u1 = *(const float4*)(A + (size_t)gr * K + kk * 32 + quad * 8 + 4);
                aReg[mi][kk][0] = (_Float16)u0.x; aReg[mi][kk][1] = (_Float16)u0.y;
                aReg[mi][kk][2] = (_Float16)u0.z; aReg[mi][kk][3] = (_Float16)u0.w;
                aReg[mi][kk][4] = (_Float16)u1.x; aReg[mi][kk][5] = (_Float16)u1.y;
                aReg[mi][kk][6] = (_Float16)u1.z; aReg[mi][kk][7] = (_Float16)u1.w;
            }
        }
    } else {
        const _Float16* A = (const _Float16*)Av;
        #pragma unroll
        for (int mi = 0; mi < 2; ++mi) {
            const int gr = mi ? gr1 : gr0;
            #pragma unroll
            for (int kk = 0; kk < 8; ++kk)
                aReg[mi][kk] = *(const half8*)(A + (size_t)gr * K + kk * 32 + quad * 8);
        }
    }

    f32x4 acc[2][16] = {};
    const _Float16* Bbase = Wt + (size_t)l16 * K + quad * 8;

    #pragma unroll
    for (int ni = 0; ni < 16; ++ni) {
        half8 bf[8];
        #pragma unroll
        for (int kk = 0; kk < 8; ++kk)
            bf[kk] = *(const half8*)(Bbase + (size_t)(ni * 16) * K + kk * 32);
        #pragma unroll
        for (int kk = 0; kk < 8; ++kk) {
            acc[0][ni] = __builtin_amdgcn_mfma_f32_16x16x32_f16(
                aReg[0][kk], bf[kk], acc[0][ni], 0, 0, 0);
            acc[1][ni] = __builtin_amdgcn_mfma_f32_16x16x32_f16(
                aReg[1][kk], bf[kk], acc[1][ni], 0, 0, 0);
        }
    }

    // epilogue: C/D layout col=lane&15, row=quad*4+reg
    #pragma unroll
    for (int ci = 0; ci < 16; ++ci) {
        const int col = ci * 16 + l16;
        const float b = bias[col];
        #pragma unroll
        for (int mi = 0; mi < 2; ++mi) {
            #pragma unroll
            for (int r = 0; r < 4; ++r) {
                const int grow = row0 + wave * 32 + mi * 16 + quad * 4 + r;
                if (grow < M) {
                    const float v = fmaxf(acc[mi][ci][r] + b, 0.f);
                    out[(size_t)grow * K + col] = (_Float16)v;
                }
            }
        }
    }
}

// --- MFMA FC v2: logits[M x 40] = h[M x 256] @ wfcT^T + bfc. LDS-free.
__global__ __launch_bounds__(256) void fc_mfma(
    const _Float16* __restrict__ h, const _Float16* __restrict__ WfcT,
    const float* __restrict__ bfc, float* __restrict__ logits, int M)
{
    constexpr int K = 256;
    const int tid  = threadIdx.x;
    const int wave = tid >> 6;
    const int lane = tid & 63;
    const int quad = lane >> 4;
    const int l16  = lane & 15;
    const int row0 = blockIdx.x * 128;

    const int gr0 = min(row0 + wave * 32 + l16,      M - 1);
    const int gr1 = min(row0 + wave * 32 + 16 + l16, M - 1);

    f32x4 acc[2][3] = {};
    const _Float16* Bbase = WfcT + (size_t)l16 * K + quad * 8;

    #pragma unroll
    for (int kk = 0; kk < 8; ++kk) {
        const half8 af0 = *(const half8*)(h + (size_t)gr0 * K + kk * 32 + quad * 8);
        const half8 af1 = *(const half8*)(h + (size_t)gr1 * K + kk * 32 + quad * 8);
        #pragma unroll
        for (int ni = 0; ni < 3; ++ni) {
            const half8 bf = *(const half8*)(Bbase + (size_t)(ni * 16) * K + kk * 32);
            acc[0][ni] = __builtin_amdgcn_mfma_f32_16x16x32_f16(af0, bf, acc[0][ni], 0, 0, 0);
            acc[1][ni] = __builtin_amdgcn_mfma_f32_16x16x32_f16(af1, bf, acc[1][ni], 0, 0, 0);
        }
    }

    #pragma unroll
    for (int ni = 0; ni < 3; ++ni) {
        const int col = ni * 16 + l16;
        if (col >= C_DIM) continue;
        const float b = bfc[col];
        #pragma unroll
        for (int mi = 0; mi < 2; ++mi) {
            #pragma unroll
            for (int r = 0; r < 4; ++r) {
                const int grow = row0 + wave * 32 + mi * 16 + quad * 4 + r;
                if (grow < M)
                    logits[(size_t)grow * C_DIM + col] = acc[mi][ni][r] + b;
            }
        }
    }
}

// --- bucket CSR: LDS-reorder chunk by bucket, emit contiguous runs.
//     packed edge = (src<<8) | (dst&255). Counts from cntMat, bases baseMat.
__global__ __launch_bounds__(256) void bucket_scatter(
    const int* __restrict__ src, const int* __restrict__ dst,
    const int* __restrict__ cntMat, const int* __restrict__ baseMat,
    int* __restrict__ packed, int E, int chunk)
{
    __shared__ int lcnt[NBUCK], loff[NBUCK], cursor[NBUCK], gbase[NBUCK];
    __shared__ int segSum[4];
    __shared__ int ldsOut[MAXCHUNK];
    const int tid  = threadIdx.x;
    const int wave = tid >> 6;
    const int lane = tid & 63;
    const int k    = blockIdx.x;
    const int e0 = k * chunk;
    const int e1 = min(e0 + chunk, E);

    lcnt[tid]  = cntMat[tid * NB + k];
    gbase[tid] = baseMat[tid * NB + k];
    __syncthreads();

    // exclusive scan lcnt -> loff (4 waves x 64)
    {
        const int v = lcnt[tid];
        int s = v;
        #pragma unroll
        for (int off = 1; off < 64; off <<= 1) {
            const int t = __shfl_up(s, off, 64);
            if (lane >= off) s += t;
        }
        loff[tid] = s - v;
        if (lane == 63) segSum[wave] = s;
    }
    __syncthreads();
    if (tid == 0) {
        int c = 0;
        #pragma unroll
        for (int w = 0; w < 4; ++w) { const int t = segSum[w]; segSum[w] = c; c += t; }
    }
    __syncthreads();
    loff[tid] += segSum[wave];
    cursor[tid] = 0;
    __syncthreads();

    // read chunk, place packed values bucket-ordered in LDS
    for (int i = e0 + tid; i < e1; i += 256) {
        const int d = dst[i];
        const int b = d >> 8;
        const int pos = atomicAdd(&cursor[b], 1);
        ldsOut[loff[b] + pos] = (src[i] << 8) | (d & 255);
    }
    __syncthreads();

    // emit each bucket's run contiguously (wave per bucket rr)
    for (int b = wave; b < NBUCK; b += 4) {
        const int cnt = lcnt[b];
        const int gb  = gbase[b];
        const int lb  = loff[b];
        for (int j = lane; j < cnt; j += 64)
            packed[gb + j] = ldsOut[lb + j];
    }
}

// --- bucket CSR: per-bucket node histogram -> rowptr/rowEnd + ordered csr_src
__global__ __launch_bounds__(256) void bucket_to_csr(
    const int* __restrict__ packed, const int* __restrict__ baseMat,
    const int* __restrict__ bEnd, int* __restrict__ rowptr,
    int* __restrict__ rowEnd, int* __restrict__ csr_src, int N)
{
    __shared__ int lcnt[NBUCK], loff[NBUCK], cursor[NBUCK];
    __shared__ int segSum[4];
    const int tid  = threadIdx.x;
    const int wave = tid >> 6;
    const int lane = tid & 63;
    const int b    = blockIdx.x;
    const int nodeBase = b * NBUCK;
    if (nodeBase >= N) return;              // bucket beyond node range

    const int gbeg = baseMat[b * NB];
    const int gend = bEnd[b];

    lcnt[tid] = 0;
    __syncthreads();

    // histogram of low-8 node ids
    for (int e = gbeg + tid; e < gend; e += 256)
        atomicAdd(&lcnt[packed[e] & 255], 1);
    __syncthreads();

    // exclusive scan lcnt -> loff
    {
        const int v = lcnt[tid];
        int s = v;
        #pragma unroll
        for (int off = 1; off < 64; off <<= 1) {
            const int t = __shfl_up(s, off, 64);
            if (lane >= off) s += t;
        }
        loff[tid] = s - v;
        if (lane == 63) segSum[wave] = s;
    }
    __syncthreads();
    if (tid == 0) {
        int c = 0;
        #pragma unroll
        for (int w = 0; w < 4; ++w) { const int t = segSum[w]; segSum[w] = c; c += t; }
    }
    __syncthreads();
    loff[tid] += segSum[wave];
    cursor[tid] = 0;
    __syncthreads();

    // rowptr/rowEnd for owned nodes
    if (nodeBase + tid < N) {
        rowptr[nodeBase + tid] = gbeg + loff[tid];
        rowEnd[nodeBase + tid] = gbeg + loff[tid] + lcnt[tid];
    }
    __syncthreads();

    // scatter src ids ordered by node (block-owned region)
    for (int e = gbeg + tid; e < gend; e += 256) {
        const int p = packed[e];
        const int node = p & 255;
        const int pos = atomicAdd(&cursor[node], 1);
        csr_src[gbeg + loff[node] + pos] = p >> 8;
    }
}

// --- conv aggregate: h[row] = f16(relu(msg[row] + sum_{in-edges} msg[src]))
//     2 rows per wave (32 lanes x half8 each); edge loop unrolled x8.
__global__ __launch_bounds__(512) void csr_gather_f16(
    const _Float16* __restrict__ msg, const int* __restrict__ rowptr,
    const int* __restrict__ rowEnd, const int* __restrict__ csr_src,
    _Float16* __restrict__ h, int N)
{
    const int tid  = threadIdx.x;
    const int wave = tid >> 6;
    const int lane = tid & 63;
    const int g    = lane >> 5;              // row within wave (0/1)
    const int rl   = lane & 31;              // lane within row-group
    const int gsrc = lane & 32;              // shuffle base of this group
    const int row  = (blockIdx.x * 8 + wave) * 2 + g;
    if (row >= N) return;

    const int beg = rowptr[row];
    const int end = rowEnd[row];
    const size_t fofs = (size_t)rl * 8;

    const half8 self = *(const half8*)(msg + (size_t)row * F_DIM + fofs);
    float a[8];
    #pragma unroll
    for (int i = 0; i < 8; ++i) a[i] = (float)self[i];

    for (int e0 = beg; e0 < end; e0 += 32) {
        const int n  = min(32, end - e0);
        const int sv = (e0 + rl < end) ? csr_src[e0 + rl] : 0;
        int j = 0;
        for (; j + 8 <= n; j += 8) {
            int s[8];
            #pragma unroll
            for (int u = 0; u < 8; ++u) s[u] = __shfl(sv, gsrc + j + u, 64);
            half8 v[8];
            #pragma unroll
            for (int u = 0; u < 8; ++u)
                v[u] = *(const half8*)(msg + (size_t)s[u] * F_DIM + fofs);
            #pragma unroll
            for (int u = 0; u < 8; ++u)
                #pragma unroll
                for (int i = 0; i < 8; ++i) a[i] += (float)v[u][i];
        }
        for (; j < n; ++j) {
            const int s = __shfl(sv, gsrc + j, 64);
            const half8 v = *(const half8*)(msg + (size_t)s * F_DIM + fofs);
            #pragma unroll
            for (int i = 0; i < 8; ++i) a[i] += (float)v[i];
        }
    }

    half8 o;
    #pragma unroll
    for (int i = 0; i < 8; ++i) o[i] = (_Float16)fmaxf(a[i], 0.f);
    *(half8*)(h + (size_t)row * F_DIM + fofs) = o;
}

// --- sparse PvT: out[prow[i]] += pval[i] * logits[pcol[i]], wave/nnz
__global__ __launch_bounds__(256) void pvt_scatter(
    const float* __restrict__ logits, const int* __restrict__ prow,
    const int* __restrict__ pcol, const float* __restrict__ pval,
    float* __restrict__ out, int nnz)
{
    const int i    = (blockIdx.x * 256 + threadIdx.x) >> 6;
    const int lane = threadIdx.x & 63;
    if (i >= nnz || lane >= C_DIM) return;
    const int r = prow[i];
    const int c = pcol[i];
    const float v = pval[i];
    atomicAdd(out + (size_t)r * C_DIM + lane, v * logits[(size_t)c * C_DIM + lane]);
}

// --- row-wise log_softmax in place, wave/row (lanes 0..39 active)
__global__ __launch_bounds__(256) void log_softmax40(float* __restrict__ out, int M)
{
    const int row  = (blockIdx.x * 256 + threadIdx.x) >> 6;
    const int lane = threadIdx.x & 63;
    if (row >= M) return;
    const float v = (lane < C_DIM) ? out[(size_t)row * C_DIM + lane] : -INFINITY;
    float m = v;
    #pragma unroll
    for (int off = 32; off >= 1; off >>= 1)
        m = fmaxf(m, __shfl_xor(m, off, 64));
    float e = (lane < C_DIM) ? expf(v - m) : 0.f;
    float s = e;
    #pragma unroll
    for (int off = 32; off >= 1; off >>= 1)
        s += __shfl_xor(s, off, 64);
    if (lane < C_DIM)
        out[(size_t)row * C_DIM + lane] = v - m - logf(s);
}

extern "C" void kernel_launch(void* const* d_in, const int* in_sizes, int n_in,
                              void* d_out, int out_size, void* d_ws, size_t ws_size,
                              hipStream_t stream)
{
    const float* x        = (const float*)d_in[0];
    const int*   edge_src = (const int*)d_in[1];
    const int*   edge_dst = (const int*)d_in[2];
    const int*   pvt_row  = (const int*)d_in[3];
    const int*   pvt_col  = (const int*)d_in[4];
    const float* pvt_val  = (const float*)d_in[5];
    const float* w1       = (const float*)d_in[6];
    const float* b1       = (const float*)d_in[7];
    const float* w2       = (const float*)d_in[8];
    const float* b2       = (const float*)d_in[9];
    const float* wfc      = (const float*)d_in[10];
    const float* bfc      = (const float*)d_in[11];

    const int N   = in_sizes[0] / F_DIM;   // 50000
    const int E   = in_sizes[1];           // 1600000
    const int NNZ = in_sizes[3];           // 50000

    float* out = (float*)d_out;

    // workspace layout
    const size_t nodeElems = (size_t)N * F_DIM;
    _Float16* w1t     = (_Float16*)d_ws;              // 256*256 fp16
    _Float16* w2t     = w1t + 65536;                  // 256*256 fp16
    _Float16* wfcT    = w2t + 65536;                  // 48*256 fp16
    _Float16* bufM    = wfcT + 48 * 256;              // msg, N*256 fp16
    _Float16* bufH    = bufM + nodeElems;             // h,   N*256 fp16
    float*    logits  = (float*)(bufH + nodeElems);   // N x 40 f32
    int*      cntMat  = (int*)(logits + (size_t)N * C_DIM); // 65536
    int*      baseMat = cntMat + 65536;               // 65536
    int*      bEnd    = baseMat + 65536;              // 256
    int*      gctr    = bEnd + 256;                   // 1 (+pad)
    int*      rowptr  = gctr + 8;                     // N
    int*      rowEnd  = rowptr + N + 8;               // N
    int*      csr_src = rowEnd + N + 8;               // E
    int*      packed  = csr_src + E;                  // E

    const int chunk = (E + NB - 1) / NB;              // 6250, <= MAXCHUNK

    const int gemmBlocks  = (N + 127) / 128;
    const int fcBlocks    = (N + 127) / 128;
    const int rowBlocks   = (N + 3) / 4;
    const int gatherBlocks= (N + 15) / 16;            // 16 rows per 512-blk
    const int nnzBlocks   = (NNZ + 3) / 4;

    // === prep: bucket histograms + weight conversions + gctr=0 ===
    prep<<<NB + 768, 256, 0, stream>>>(edge_dst, cntMat, E, chunk,
                                       w1, w2, wfc, w1t, w2t, wfcT, gctr);

    // === bucket-sort CSR build (order-free bases) ===
    bucket_alloc<<<NBUCK, 256, 0, stream>>>(cntMat, baseMat, bEnd, gctr);
    bucket_scatter<<<NB, 256, 0, stream>>>(edge_src, edge_dst, cntMat, baseMat,
                                           packed, E, chunk);
    bucket_to_csr<<<NBUCK, 256, 0, stream>>>(packed, baseMat, bEnd,
                                             rowptr, rowEnd, csr_src, N);

    // === layer 1 (A = fp32 x, converted inline) ===
    gemm_f16<true><<<gemmBlocks, 256, 0, stream>>>(x, w1t, b1, bufM, N);
    csr_gather_f16<<<gatherBlocks, 512, 0, stream>>>(bufM, rowptr, rowEnd,
                                                     csr_src, bufH, N);

    // === layer 2 ===
    gemm_f16<false><<<gemmBlocks, 256, 0, stream>>>(bufH, w2t, b2, bufM, N);
    csr_gather_f16<<<gatherBlocks, 512, 0, stream>>>(bufM, rowptr, rowEnd,
                                                     csr_src, bufH, N);

    // === FC (MFMA, LDS-free) ===
    fc_mfma<<<fcBlocks, 256, 0, stream>>>(bufH, wfcT, bfc, logits, N);

    // === PvT scatter into d_out, then log_softmax ===
    hipMemsetAsync(d_out, 0, (size_t)N * C_DIM * sizeof(float), stream);
    pvt_scatter<<<nnzBlocks, 256, 0, stream>>>(logits, pvt_row, pvt_col, pvt_val, out, NNZ);
    log_softmax40<<<rowBlocks, 256, 0, stream>>>(out, N);
}

// Round 13
// 476.016 us; speedup vs baseline: 1.1190x; 1.1190x over previous
//
#include <hip/hip_runtime.h>
#include <hip/hip_bf16.h>
#include <math.h>

// ---------------------------------------------------------------------------
// MPNN node classifier.
// R12: revert R11's LDS-free GEMM/FC (B-load latency serialized the MFMA
// chain; cold gemm 145->166us). Restore R10 GEMM v3 (A-stripe in regs, B
// staged in LDS per 128-col half). KEEP R11's order-free bucket_alloc +
// rowptr/rowEnd (removes the single-CU serial scan).
// ---------------------------------------------------------------------------

#define F_DIM 256   // F_IN == H == 256
#define C_DIM 40
#define NBUCK 256   // coarse buckets: dst >> 8
#define NB    256   // scatter blocks (chunks)
#define MAXCHUNK 6400

typedef _Float16 half8 __attribute__((ext_vector_type(8)));
typedef float    f32x4 __attribute__((ext_vector_type(4)));

// --- merged prep: blocks [0,NB) = bucket_count chunk histograms;
//     [NB,NB+256) w1 cvt; [NB+512) w2 cvt; [NB+768) wfc cvt+pad.
//     Block NB thread 0 also zeroes the bucket-base allocator counter.
__global__ __launch_bounds__(256) void prep(
    const int* __restrict__ dst, int* __restrict__ cntMat, int E, int chunk,
    const float* __restrict__ w1, const float* __restrict__ w2,
    const float* __restrict__ wfc, _Float16* __restrict__ w1t,
    _Float16* __restrict__ w2t, _Float16* __restrict__ wfcT,
    int* __restrict__ gctr)
{
    __shared__ int lcnt[NBUCK];
    const int tid = threadIdx.x;
    const int bid = blockIdx.x;
    if (bid < NB) {
        lcnt[tid] = 0;
        __syncthreads();
        const int e0 = bid * chunk;
        const int e1 = min(e0 + chunk, E);
        for (int i = e0 + tid; i < e1; i += 256)
            atomicAdd(&lcnt[dst[i] >> 8], 1);
        __syncthreads();
        cntMat[tid * NB + bid] = lcnt[tid];
    } else {
        if (bid == NB && tid == 0) *gctr = 0;
        const int r = bid - NB;
        const int k = r & 255;
        const int y = r >> 8;
        const int n = tid;
        if (y == 0)      w1t[n * 256 + k] = (_Float16)w1[k * 256 + n];
        else if (y == 1) w2t[n * 256 + k] = (_Float16)w2[k * 256 + n];
        else if (n < 48)
            wfcT[n * 256 + k] = (n < C_DIM) ? (_Float16)wfc[k * C_DIM + n]
                                            : (_Float16)0.f;
    }
}

// --- order-free bucket base allocation: block b scans its 256 chunk counts,
//     grabs a contiguous region via device-scope atomicAdd.
__global__ __launch_bounds__(256) void bucket_alloc(
    const int* __restrict__ cntMat, int* __restrict__ baseMat,
    int* __restrict__ bEnd, int* __restrict__ gctr)
{
    __shared__ int segSum[4];
    __shared__ int baseSh;
    const int tid  = threadIdx.x;
    const int wave = tid >> 6;
    const int lane = tid & 63;
    const int b    = blockIdx.x;

    const int v = cntMat[b * NB + tid];
    int s = v;                              // inclusive wave scan
    #pragma unroll
    for (int off = 1; off < 64; off <<= 1) {
        const int t = __shfl_up(s, off, 64);
        if (lane >= off) s += t;
    }
    if (lane == 63) segSum[wave] = s;
    __syncthreads();
    if (tid == 0) {
        int c = 0;
        #pragma unroll
        for (int w = 0; w < 4; ++w) { const int t = segSum[w]; segSum[w] = c; c += t; }
        baseSh = atomicAdd(gctr, c);        // c = bucket total
    }
    __syncthreads();
    const int excl = baseSh + segSum[wave] + (s - v);
    baseMat[b * NB + tid] = excl;
    if (tid == 255) bEnd[b] = excl + v;
}

// --- MFMA fp16 GEMM v3 (R10): out = f16(relu(A @ Wt^T + bias)).
//     Wave caches its full A stripe in registers; B staged per 128-col half
//     into one 67.6KB LDS buffer.
template <bool AF32>
__global__ __launch_bounds__(256, 2) void gemm_f16(
    const void* __restrict__ Av, const _Float16* __restrict__ Wt,
    const float* __restrict__ bias, _Float16* __restrict__ out, int M)
{
    constexpr int K = 256;
    constexpr int LDB = 264;                // 132 words ≡ 4 mod 32: conflict-free
    __shared__ _Float16 Bs[128 * LDB];

    const int tid  = threadIdx.x;
    const int wave = tid >> 6;
    const int lane = tid & 63;
    const int quad = lane >> 4;
    const int l16  = lane & 15;
    const int row0 = blockIdx.x * 128;

    const int gr0 = min(row0 + wave * 32 + l16,      M - 1);
    const int gr1 = min(row0 + wave * 32 + 16 + l16, M - 1);

    // cache full A stripe: aReg[mi][kk] covers k = kk*32 + quad*8 .. +7
    half8 aReg[2][8];
    if constexpr (AF32) {
        const float* A = (const float*)Av;
        #pragma unroll
        for (int mi = 0; mi < 2; ++mi) {
            const int gr = mi ? gr1 : gr0;
            #pragma unroll
            for (int kk = 0; kk < 8; ++kk) {
                const float4 u0 = *(const float4*)(A + (size_t)gr * K + kk * 32 + quad * 8);
                const float4 u1 = *(const float4*)(A + (size_t)gr * K + kk * 32 + quad * 8 + 4);
                aReg[mi][kk][0] = (_Float16)u0.x; aReg[mi][kk][1] = (_Float16)u0.y;
                aReg[mi][kk][2] = (_Float16)u0.z; aReg[mi][kk][3] = (_Float16)u0.w;
                aReg[mi][kk][4] = (_Float16)u1.x; aReg[mi][kk][5] = (_Float16)u1.y;
                aReg[mi][kk][6] = (_Float16)u1.z; aReg[mi][kk][7] = (_Float16)u1.w;
            }
        }
    } else {
        const _Float16* A = (const _Float16*)Av;
        #pragma unroll
        for (int mi = 0; mi < 2; ++mi) {
            const int gr = mi ? gr1 : gr0;
            #pragma unroll
            for (int kk = 0; kk < 8; ++kk)
                aReg[mi][kk] = *(const half8*)(A + (size_t)gr * K + kk * 32 + quad * 8);
        }
    }

    f32x4 acc[2][16] = {};

    #pragma unroll
    for (int hf = 0; hf < 2; ++hf) {
        if (hf) __syncthreads();            // all waves done reading half-0 Bs
        // stage B half: 128 n x 256 k (coalesced; 16 chunks/thread)
        #pragma unroll
        for (int c = 0; c < 16; ++c) {
            const int idx = c * 256 + tid;
            const int n   = idx >> 5;
            const int ko  = (idx & 31) * 8;
            *(half8*)&Bs[n * LDB + ko] =
                *(const half8*)(Wt + (size_t)(hf * 128 + n) * K + ko);
        }
        __syncthreads();

        #pragma unroll
        for (int kk = 0; kk < 8; ++kk) {
            #pragma unroll
            for (int ni = 0; ni < 8; ++ni) {
                const half8 bf = *(const half8*)&Bs[(ni * 16 + l16) * LDB + kk * 32 + quad * 8];
                acc[0][hf * 8 + ni] = __builtin_amdgcn_mfma_f32_16x16x32_f16(
                    aReg[0][kk], bf, acc[0][hf * 8 + ni], 0, 0, 0);
                acc[1][hf * 8 + ni] = __builtin_amdgcn_mfma_f32_16x16x32_f16(
                    aReg[1][kk], bf, acc[1][hf * 8 + ni], 0, 0, 0);
            }
        }
    }

    // epilogue: C/D layout col=lane&15, row=quad*4+reg
    #pragma unroll
    for (int ci = 0; ci < 16; ++ci) {
        const int col = ci * 16 + l16;
        const float b = bias[col];
        #pragma unroll
        for (int mi = 0; mi < 2; ++mi) {
            #pragma unroll
            for (int r = 0; r < 4; ++r) {
                const int grow = row0 + wave * 32 + mi * 16 + quad * 4 + r;
                if (grow < M) {
                    const float v = fmaxf(acc[mi][ci][r] + b, 0.f);
                    out[(size_t)grow * K + col] = (_Float16)v;
                }
            }
        }
    }
}

// --- MFMA FC (R10): logits[M x 40] = h[M x 256] @ wfcT^T + bfc. LDS-staged B.
__global__ __launch_bounds__(256, 2) void fc_mfma(
    const _Float16* __restrict__ h, const _Float16* __restrict__ WfcT,
    const float* __restrict__ bfc, float* __restrict__ logits, int M)
{
    constexpr int K = 256;
    constexpr int LDB = 264;
    __shared__ _Float16 Bs[48 * LDB];

    const int tid  = threadIdx.x;
    const int wave = tid >> 6;
    const int lane = tid & 63;
    const int quad = lane >> 4;
    const int l16  = lane & 15;
    const int row0 = blockIdx.x * 128;

    #pragma unroll
    for (int c = 0; c < 6; ++c) {
        const int idx = c * 256 + tid;
        const int n   = idx >> 5;
        const int ko  = (idx & 31) * 8;
        *(half8*)&Bs[n * LDB + ko] = *(const half8*)(WfcT + (size_t)n * K + ko);
    }
    __syncthreads();

    const int gr0 = min(row0 + wave * 32 + l16,      M - 1);
    const int gr1 = min(row0 + wave * 32 + 16 + l16, M - 1);

    f32x4 acc[2][3] = {};

    for (int k0 = 0; k0 < K; k0 += 32) {
        half8 af[2];
        af[0] = *(const half8*)(h + (size_t)gr0 * K + k0 + quad * 8);
        af[1] = *(const half8*)(h + (size_t)gr1 * K + k0 + quad * 8);
        #pragma unroll
        for (int ni = 0; ni < 3; ++ni) {
            const half8 bf = *(const half8*)&Bs[(ni * 16 + l16) * LDB + k0 + quad * 8];
            acc[0][ni] = __builtin_amdgcn_mfma_f32_16x16x32_f16(af[0], bf, acc[0][ni], 0, 0, 0);
            acc[1][ni] = __builtin_amdgcn_mfma_f32_16x16x32_f16(af[1], bf, acc[1][ni], 0, 0, 0);
        }
    }

    #pragma unroll
    for (int ni = 0; ni < 3; ++ni) {
        const int col = ni * 16 + l16;
        if (col >= C_DIM) continue;
        const float b = bfc[col];
        #pragma unroll
        for (int mi = 0; mi < 2; ++mi) {
            #pragma unroll
            for (int r = 0; r < 4; ++r) {
                const int grow = row0 + wave * 32 + mi * 16 + quad * 4 + r;
                if (grow < M)
                    logits[(size_t)grow * C_DIM + col] = acc[mi][ni][r] + b;
            }
        }
    }
}

// --- bucket CSR: LDS-reorder chunk by bucket, emit contiguous runs.
//     packed edge = (src<<8) | (dst&255). Counts from cntMat, bases baseMat.
__global__ __launch_bounds__(256) void bucket_scatter(
    const int* __restrict__ src, const int* __restrict__ dst,
    const int* __restrict__ cntMat, const int* __restrict__ baseMat,
    int* __restrict__ packed, int E, int chunk)
{
    __shared__ int lcnt[NBUCK], loff[NBUCK], cursor[NBUCK], gbase[NBUCK];
    __shared__ int segSum[4];
    __shared__ int ldsOut[MAXCHUNK];
    const int tid  = threadIdx.x;
    const int wave = tid >> 6;
    const int lane = tid & 63;
    const int k    = blockIdx.x;
    const int e0 = k * chunk;
    const int e1 = min(e0 + chunk, E);

    lcnt[tid]  = cntMat[tid * NB + k];
    gbase[tid] = baseMat[tid * NB + k];
    __syncthreads();

    // exclusive scan lcnt -> loff (4 waves x 64)
    {
        const int v = lcnt[tid];
        int s = v;
        #pragma unroll
        for (int off = 1; off < 64; off <<= 1) {
            const int t = __shfl_up(s, off, 64);
            if (lane >= off) s += t;
        }
        loff[tid] = s - v;
        if (lane == 63) segSum[wave] = s;
    }
    __syncthreads();
    if (tid == 0) {
        int c = 0;
        #pragma unroll
        for (int w = 0; w < 4; ++w) { const int t = segSum[w]; segSum[w] = c; c += t; }
    }
    __syncthreads();
    loff[tid] += segSum[wave];
    cursor[tid] = 0;
    __syncthreads();

    // read chunk, place packed values bucket-ordered in LDS
    for (int i = e0 + tid; i < e1; i += 256) {
        const int d = dst[i];
        const int b = d >> 8;
        const int pos = atomicAdd(&cursor[b], 1);
        ldsOut[loff[b] + pos] = (src[i] << 8) | (d & 255);
    }
    __syncthreads();

    // emit each bucket's run contiguously (wave per bucket rr)
    for (int b = wave; b < NBUCK; b += 4) {
        const int cnt = lcnt[b];
        const int gb  = gbase[b];
        const int lb  = loff[b];
        for (int j = lane; j < cnt; j += 64)
            packed[gb + j] = ldsOut[lb + j];
    }
}

// --- bucket CSR: per-bucket node histogram -> rowptr/rowEnd + ordered csr_src
__global__ __launch_bounds__(256) void bucket_to_csr(
    const int* __restrict__ packed, const int* __restrict__ baseMat,
    const int* __restrict__ bEnd, int* __restrict__ rowptr,
    int* __restrict__ rowEnd, int* __restrict__ csr_src, int N)
{
    __shared__ int lcnt[NBUCK], loff[NBUCK], cursor[NBUCK];
    __shared__ int segSum[4];
    const int tid  = threadIdx.x;
    const int wave = tid >> 6;
    const int lane = tid & 63;
    const int b    = blockIdx.x;
    const int nodeBase = b * NBUCK;
    if (nodeBase >= N) return;              // bucket beyond node range

    const int gbeg = baseMat[b * NB];
    const int gend = bEnd[b];

    lcnt[tid] = 0;
    __syncthreads();

    // histogram of low-8 node ids
    for (int e = gbeg + tid; e < gend; e += 256)
        atomicAdd(&lcnt[packed[e] & 255], 1);
    __syncthreads();

    // exclusive scan lcnt -> loff
    {
        const int v = lcnt[tid];
        int s = v;
        #pragma unroll
        for (int off = 1; off < 64; off <<= 1) {
            const int t = __shfl_up(s, off, 64);
            if (lane >= off) s += t;
        }
        loff[tid] = s - v;
        if (lane == 63) segSum[wave] = s;
    }
    __syncthreads();
    if (tid == 0) {
        int c = 0;
        #pragma unroll
        for (int w = 0; w < 4; ++w) { const int t = segSum[w]; segSum[w] = c; c += t; }
    }
    __syncthreads();
    loff[tid] += segSum[wave];
    cursor[tid] = 0;
    __syncthreads();

    // rowptr/rowEnd for owned nodes
    if (nodeBase + tid < N) {
        rowptr[nodeBase + tid] = gbeg + loff[tid];
        rowEnd[nodeBase + tid] = gbeg + loff[tid] + lcnt[tid];
    }
    __syncthreads();

    // scatter src ids ordered by node (block-owned region)
    for (int e = gbeg + tid; e < gend; e += 256) {
        const int p = packed[e];
        const int node = p & 255;
        const int pos = atomicAdd(&cursor[node], 1);
        csr_src[gbeg + loff[node] + pos] = p >> 8;
    }
}

// --- conv aggregate: h[row] = f16(relu(msg[row] + sum_{in-edges} msg[src]))
//     2 rows per wave (32 lanes x half8 each); edge loop unrolled x8.
__global__ __launch_bounds__(512) void csr_gather_f16(
    const _Float16* __restrict__ msg, const int* __restrict__ rowptr,
    const int* __restrict__ rowEnd, const int* __restrict__ csr_src,
    _Float16* __restrict__ h, int N)
{
    const int tid  = threadIdx.x;
    const int wave = tid >> 6;
    const int lane = tid & 63;
    const int g    = lane >> 5;              // row within wave (0/1)
    const int rl   = lane & 31;              // lane within row-group
    const int gsrc = lane & 32;              // shuffle base of this group
    const int row  = (blockIdx.x * 8 + wave) * 2 + g;
    if (row >= N) return;

    const int beg = rowptr[row];
    const int end = rowEnd[row];
    const size_t fofs = (size_t)rl * 8;

    const half8 self = *(const half8*)(msg + (size_t)row * F_DIM + fofs);
    float a[8];
    #pragma unroll
    for (int i = 0; i < 8; ++i) a[i] = (float)self[i];

    for (int e0 = beg; e0 < end; e0 += 32) {
        const int n  = min(32, end - e0);
        const int sv = (e0 + rl < end) ? csr_src[e0 + rl] : 0;
        int j = 0;
        for (; j + 8 <= n; j += 8) {
            int s[8];
            #pragma unroll
            for (int u = 0; u < 8; ++u) s[u] = __shfl(sv, gsrc + j + u, 64);
            half8 v[8];
            #pragma unroll
            for (int u = 0; u < 8; ++u)
                v[u] = *(const half8*)(msg + (size_t)s[u] * F_DIM + fofs);
            #pragma unroll
            for (int u = 0; u < 8; ++u)
                #pragma unroll
                for (int i = 0; i < 8; ++i) a[i] += (float)v[u][i];
        }
        for (; j < n; ++j) {
            const int s = __shfl(sv, gsrc + j, 64);
            const half8 v = *(const half8*)(msg + (size_t)s * F_DIM + fofs);
            #pragma unroll
            for (int i = 0; i < 8; ++i) a[i] += (float)v[i];
        }
    }

    half8 o;
    #pragma unroll
    for (int i = 0; i < 8; ++i) o[i] = (_Float16)fmaxf(a[i], 0.f);
    *(half8*)(h + (size_t)row * F_DIM + fofs) = o;
}

// --- sparse PvT: out[prow[i]] += pval[i] * logits[pcol[i]], wave/nnz
__global__ __launch_bounds__(256) void pvt_scatter(
    const float* __restrict__ logits, const int* __restrict__ prow,
    const int* __restrict__ pcol, const float* __restrict__ pval,
    float* __restrict__ out, int nnz)
{
    const int i    = (blockIdx.x * 256 + threadIdx.x) >> 6;
    const int lane = threadIdx.x & 63;
    if (i >= nnz || lane >= C_DIM) return;
    const int r = prow[i];
    const int c = pcol[i];
    const float v = pval[i];
    atomicAdd(out + (size_t)r * C_DIM + lane, v * logits[(size_t)c * C_DIM + lane]);
}

// --- row-wise log_softmax in place, wave/row (lanes 0..39 active)
__global__ __launch_bounds__(256) void log_softmax40(float* __restrict__ out, int M)
{
    const int row  = (blockIdx.x * 256 + threadIdx.x) >> 6;
    const int lane = threadIdx.x & 63;
    if (row >= M) return;
    const float v = (lane < C_DIM) ? out[(size_t)row * C_DIM + lane] : -INFINITY;
    float m = v;
    #pragma unroll
    for (int off = 32; off >= 1; off >>= 1)
        m = fmaxf(m, __shfl_xor(m, off, 64));
    float e = (lane < C_DIM) ? expf(v - m) : 0.f;
    float s = e;
    #pragma unroll
    for (int off = 32; off >= 1; off >>= 1)
        s += __shfl_xor(s, off, 64);
    if (lane < C_DIM)
        out[(size_t)row * C_DIM + lane] = v - m - logf(s);
}

extern "C" void kernel_launch(void* const* d_in, const int* in_sizes, int n_in,
                              void* d_out, int out_size, void* d_ws, size_t ws_size,
                              hipStream_t stream)
{
    const float* x        = (const float*)d_in[0];
    const int*   edge_src = (const int*)d_in[1];
    const int*   edge_dst = (const int*)d_in[2];
    const int*   pvt_row  = (const int*)d_in[3];
    const int*   pvt_col  = (const int*)d_in[4];
    const float* pvt_val  = (const float*)d_in[5];
    const float* w1       = (const float*)d_in[6];
    const float* b1       = (const float*)d_in[7];
    const float* w2       = (const float*)d_in[8];
    const float* b2       = (const float*)d_in[9];
    const float* wfc      = (const float*)d_in[10];
    const float* bfc      = (const float*)d_in[11];

    const int N   = in_sizes[0] / F_DIM;   // 50000
    const int E   = in_sizes[1];           // 1600000
    const int NNZ = in_sizes[3];           // 50000

    float* out = (float*)d_out;

    // workspace layout
    const size_t nodeElems = (size_t)N * F_DIM;
    _Float16* w1t     = (_Float16*)d_ws;              // 256*256 fp16
    _Float16* w2t     = w1t + 65536;                  // 256*256 fp16
    _Float16* wfcT    = w2t + 65536;                  // 48*256 fp16
    _Float16* bufM    = wfcT + 48 * 256;              // msg, N*256 fp16
    _Float16* bufH    = bufM + nodeElems;             // h,   N*256 fp16
    float*    logits  = (float*)(bufH + nodeElems);   // N x 40 f32
    int*      cntMat  = (int*)(logits + (size_t)N * C_DIM); // 65536
    int*      baseMat = cntMat + 65536;               // 65536
    int*      bEnd    = baseMat + 65536;              // 256
    int*      gctr    = bEnd + 256;                   // 1 (+pad)
    int*      rowptr  = gctr + 8;                     // N
    int*      rowEnd  = rowptr + N + 8;               // N
    int*      csr_src = rowEnd + N + 8;               // E
    int*      packed  = csr_src + E;                  // E

    const int chunk = (E + NB - 1) / NB;              // 6250, <= MAXCHUNK

    const int gemmBlocks  = (N + 127) / 128;
    const int fcBlocks    = (N + 127) / 128;
    const int rowBlocks   = (N + 3) / 4;
    const int gatherBlocks= (N + 15) / 16;            // 16 rows per 512-blk
    const int nnzBlocks   = (NNZ + 3) / 4;

    // === prep: bucket histograms + weight conversions + gctr=0 ===
    prep<<<NB + 768, 256, 0, stream>>>(edge_dst, cntMat, E, chunk,
                                       w1, w2, wfc, w1t, w2t, wfcT, gctr);

    // === bucket-sort CSR build (order-free bases) ===
    bucket_alloc<<<NBUCK, 256, 0, stream>>>(cntMat, baseMat, bEnd, gctr);
    bucket_scatter<<<NB, 256, 0, stream>>>(edge_src, edge_dst, cntMat, baseMat,
                                           packed, E, chunk);
    bucket_to_csr<<<NBUCK, 256, 0, stream>>>(packed, baseMat, bEnd,
                                             rowptr, rowEnd, csr_src, N);

    // === layer 1 (A = fp32 x, converted inline) ===
    gemm_f16<true><<<gemmBlocks, 256, 0, stream>>>(x, w1t, b1, bufM, N);
    csr_gather_f16<<<gatherBlocks, 512, 0, stream>>>(bufM, rowptr, rowEnd,
                                                     csr_src, bufH, N);

    // === layer 2 ===
    gemm_f16<false><<<gemmBlocks, 256, 0, stream>>>(bufH, w2t, b2, bufM, N);
    csr_gather_f16<<<gatherBlocks, 512, 0, stream>>>(bufM, rowptr, rowEnd,
                                                     csr_src, bufH, N);

    // === FC (MFMA) ===
    fc_mfma<<<fcBlocks, 256, 0, stream>>>(bufH, wfcT, bfc, logits, N);

    // === PvT scatter into d_out, then log_softmax ===
    hipMemsetAsync(d_out, 0, (size_t)N * C_DIM * sizeof(float), stream);
    pvt_scatter<<<nnzBlocks, 256, 0, stream>>>(logits, pvt_row, pvt_col, pvt_val, out, NNZ);
    log_softmax40<<<rowBlocks, 256, 0, stream>>>(out, N);
}